// Round 6
// baseline (363.574 us; speedup 1.0000x reference)
//
#include <hip/hip_runtime.h>
#include <math.h>

#define BATCH 32
#define SEQ   4096
#define HD    1024

typedef float floatx4 __attribute__((ext_vector_type(4)));

// ---------------------------------------------------------------------------
// Single fused kernel: score + online-softmax + weighted accumulate, with the
// cross-chunk combine folded in via a last-block-done per-batch counter
// (saves the pass2 dispatch + inter-kernel gap). Combine runs in a fixed
// order -> bitwise deterministic regardless of block arrival order.
// ---------------------------------------------------------------------------

__device__ __forceinline__ void load_row(const float* __restrict__ vb,
                                         int s, int lane, float4* vf)
{
    const floatx4* v4 = (const floatx4*)(vb + (size_t)s * HD);
#pragma unroll
    for (int k = 0; k < 4; ++k) {
        floatx4 t = __builtin_nontemporal_load(&v4[k * 64 + lane]);
        vf[k] = make_float4(t.x, t.y, t.z, t.w);
    }
}

__device__ __forceinline__ void process_row(const float4* vf,
                                            const float4* qf,
                                            float scale_r,
                                            float& m, float& l, float4* acc)
{
    float d = 0.f;
#pragma unroll
    for (int k = 0; k < 4; ++k)
        d += vf[k].x * qf[k].x + vf[k].y * qf[k].y
           + vf[k].z * qf[k].z + vf[k].w * qf[k].w;
#pragma unroll
    for (int off = 32; off >= 1; off >>= 1)
        d += __shfl_xor(d, off, 64);

    const float sc = d * scale_r;
    const float mn = fmaxf(m, sc);          // branchless online-softmax
    const float f  = __expf(m - mn);        // first row: exp(-inf)=0 zeroes acc
    const float p  = __expf(sc - mn);
    l = l * f + p;
#pragma unroll
    for (int k = 0; k < 4; ++k) {
        acc[k].x = acc[k].x * f + p * vf[k].x;
        acc[k].y = acc[k].y * f + p * vf[k].y;
        acc[k].z = acc[k].z * f + p * vf[k].z;
        acc[k].w = acc[k].w * f + p * vf[k].w;
    }
    m = mn;
}

template <int CPB>
__global__ __launch_bounds__(256)
void luong_fused(const float* __restrict__ q,
                 const float* __restrict__ v,
                 const float* __restrict__ scale,
                 float* __restrict__ ws_acc,        // [BATCH*CPB][HD]
                 float* __restrict__ ws_m,          // [BATCH*CPB]
                 float* __restrict__ ws_l,          // [BATCH*CPB]
                 unsigned int* __restrict__ counters, // [BATCH], zeroed pre-launch
                 float* __restrict__ out)           // [BATCH][HD]
{
    constexpr int ROWS = SEQ / CPB;   // rows per block
    constexpr int RPW  = ROWS / 4;    // rows per wave (32 for CPB=32)
    static_assert(RPW >= 4 && (RPW % 2) == 0, "pipeline shape");

    const int blk  = blockIdx.x;
    const int b    = blk / CPB;
    const int ch   = blk % CPB;
    const int tid  = threadIdx.x;
    const int wid  = tid >> 6;
    const int lane = tid & 63;

    const float4* q4 = (const float4*)(q + (size_t)b * HD);
    float4 qf[4];
#pragma unroll
    for (int k = 0; k < 4; ++k) qf[k] = q4[k * 64 + lane];

    const int s0 = ch * ROWS + wid * RPW;
    const float* vb = v + (size_t)b * SEQ * HD;

    float scl = 0.f;
    if constexpr (RPW <= 64) {
        scl = (lane < RPW) ? scale[s0 + lane] : 0.f;
    }
    auto get_scale = [&](int r) -> float {
        if constexpr (RPW <= 64) return __shfl(scl, r, 64);
        else                     return scale[s0 + r];
    };

    float  m = -INFINITY, l = 0.f;
    float4 acc[4];
#pragma unroll
    for (int k = 0; k < 4; ++k) acc[k] = make_float4(0.f, 0.f, 0.f, 0.f);

    float4 va[4], vbuf[4];
    load_row(vb, s0, lane, va);
#pragma unroll 1
    for (int r = 0; r < RPW - 2; r += 2) {
        load_row(vb, s0 + r + 1, lane, vbuf);
        process_row(va, qf, get_scale(r), m, l, acc);
        load_row(vb, s0 + r + 2, lane, va);
        process_row(vbuf, qf, get_scale(r + 1), m, l, acc);
    }
    load_row(vb, s0 + RPW - 1, lane, vbuf);
    process_row(va, qf, get_scale(RPW - 2), m, l, acc);
    process_row(vbuf, qf, get_scale(RPW - 1), m, l, acc);

    // ---- combine the 4 waves of this block through LDS ----
    __shared__ float lds_m[4], lds_l[4];
    __shared__ float lds_acc[4][HD];
    if (lane == 0) { lds_m[wid] = m; lds_l[wid] = l; }
    __syncthreads();
    const float M  = fmaxf(fmaxf(lds_m[0], lds_m[1]), fmaxf(lds_m[2], lds_m[3]));
    const float fw = __expf(m - M);
    float4* la = (float4*)lds_acc[wid];
#pragma unroll
    for (int k = 0; k < 4; ++k) {
        float4 t;
        t.x = acc[k].x * fw; t.y = acc[k].y * fw;
        t.z = acc[k].z * fw; t.w = acc[k].w * fw;
        la[k * 64 + lane] = t;
    }
    __syncthreads();

    float lblk = 0.f;
#pragma unroll
    for (int w = 0; w < 4; ++w) lblk += lds_l[w] * __expf(lds_m[w] - M);

    const float4 a0 = ((const float4*)lds_acc[0])[tid];
    const float4 a1 = ((const float4*)lds_acc[1])[tid];
    const float4 a2 = ((const float4*)lds_acc[2])[tid];
    const float4 a3 = ((const float4*)lds_acc[3])[tid];
    float4 sum;
    sum.x = a0.x + a1.x + a2.x + a3.x;
    sum.y = a0.y + a1.y + a2.y + a3.y;
    sum.z = a0.z + a1.z + a2.z + a3.z;
    sum.w = a0.w + a1.w + a2.w + a3.w;
    ((float4*)(ws_acc + (size_t)blk * HD))[tid] = sum;
    if (tid == 0) { ws_m[blk] = M; ws_l[blk] = lblk; }

    // ---- last-block-done cross-chunk combine (device-scope) ----
    __threadfence();                         // release partials
    __shared__ unsigned int s_old;
    if (tid == 0) s_old = atomicAdd(&counters[b], 1u);
    __syncthreads();
    if (s_old != CPB - 1) return;            // not the last block of batch b
    __threadfence();                         // acquire others' partials

    float Mb = -INFINITY;
#pragma unroll
    for (int i = 0; i < CPB; ++i) Mb = fmaxf(Mb, ws_m[b * CPB + i]);
    float T = 0.f;
#pragma unroll
    for (int i = 0; i < CPB; ++i) T += ws_l[b * CPB + i] * __expf(ws_m[b * CPB + i] - Mb);
    const float invT = 1.f / T;

    float4 s = make_float4(0.f, 0.f, 0.f, 0.f);
#pragma unroll
    for (int i = 0; i < CPB; ++i) {          // fixed order -> deterministic
        const float wi = __expf(ws_m[b * CPB + i] - Mb) * invT;
        const float4 a = ((const float4*)(ws_acc + (size_t)(b * CPB + i) * HD))[tid];
        s.x += wi * a.x; s.y += wi * a.y;
        s.z += wi * a.z; s.w += wi * a.w;
    }
    ((float4*)(out + (size_t)b * HD))[tid] = s;
}

// ---------------------------------------------------------------------------
template <int CPB>
static void launch_impl(const float* q, const float* v, const float* scale,
                        float* out, float* ws, hipStream_t stream)
{
    const int NB = BATCH * CPB;
    float* ws_acc = ws;
    float* ws_m   = ws + (size_t)NB * HD;
    float* ws_l   = ws_m + NB;
    unsigned int* counters = (unsigned int*)(ws_l + NB);
    hipMemsetAsync(counters, 0, BATCH * sizeof(unsigned int), stream);
    luong_fused<CPB><<<NB, 256, 0, stream>>>(q, v, scale, ws_acc, ws_m, ws_l,
                                             counters, out);
}

extern "C" void kernel_launch(void* const* d_in, const int* in_sizes, int n_in,
                              void* d_out, int out_size, void* d_ws, size_t ws_size,
                              hipStream_t stream)
{
    const float* q     = (const float*)d_in[0];   // [B, H]
    const float* v     = (const float*)d_in[1];   // [B, S, H]
    const float* scale = (const float*)d_in[2];   // [S, 1]
    float* out = (float*)d_out;                   // [B, H]
    float* ws  = (float*)d_ws;

    int cpb = 32;
    while (cpb > 1 &&
           (size_t)BATCH * cpb * (HD + 2) * sizeof(float)
             + BATCH * sizeof(unsigned int) > ws_size)
        cpb >>= 1;

    switch (cpb) {
        case 32: launch_impl<32>(q, v, scale, out, ws, stream); break;
        case 16: launch_impl<16>(q, v, scale, out, ws, stream); break;
        case 8:  launch_impl<8>(q, v, scale, out, ws, stream); break;
        case 4:  launch_impl<4>(q, v, scale, out, ws, stream); break;
        case 2:  launch_impl<2>(q, v, scale, out, ws, stream); break;
        default: launch_impl<1>(q, v, scale, out, ws, stream); break;
    }
}

// Round 7
// 94.746 us; speedup vs baseline: 3.8374x; 3.8374x over previous
//
#include <hip/hip_runtime.h>
#include <math.h>

#define BATCH 32
#define SEQ   4096
#define HD    1024

typedef float floatx4 __attribute__((ext_vector_type(4)));

// ---------------------------------------------------------------------------
// R7 = R5 two-kernel structure (branchless online softmax, NT loads, scale
// hoisted to lane regs) + pair-wise software pipeline: process rows (r,r+1)
// from buffers A0/A1 while rows (r+2,r+3) load into B0/B1 -> 8 dwordx4 in
// flight per wave (2x the MLP of R5). No launch_bounds VGPR cap (R2's
// forced cap caused spills; natural pressure here is ~115 VGPR).
// ---------------------------------------------------------------------------

__device__ __forceinline__ void load_row(const float* __restrict__ vb,
                                         int s, int lane, float4* vf)
{
    const floatx4* v4 = (const floatx4*)(vb + (size_t)s * HD);
#pragma unroll
    for (int k = 0; k < 4; ++k) {
        floatx4 t = __builtin_nontemporal_load(&v4[k * 64 + lane]);
        vf[k] = make_float4(t.x, t.y, t.z, t.w);
    }
}

__device__ __forceinline__ void process_row(const float4* vf,
                                            const float4* qf,
                                            float scale_r,
                                            float& m, float& l, float4* acc)
{
    float d = 0.f;
#pragma unroll
    for (int k = 0; k < 4; ++k)
        d += vf[k].x * qf[k].x + vf[k].y * qf[k].y
           + vf[k].z * qf[k].z + vf[k].w * qf[k].w;
#pragma unroll
    for (int off = 32; off >= 1; off >>= 1)
        d += __shfl_xor(d, off, 64);

    const float sc = d * scale_r;
    const float mn = fmaxf(m, sc);          // branchless online-softmax
    const float f  = __expf(m - mn);        // first row: exp(-inf)=0 zeroes acc
    const float p  = __expf(sc - mn);
    l = l * f + p;
#pragma unroll
    for (int k = 0; k < 4; ++k) {
        acc[k].x = acc[k].x * f + p * vf[k].x;
        acc[k].y = acc[k].y * f + p * vf[k].y;
        acc[k].z = acc[k].z * f + p * vf[k].z;
        acc[k].w = acc[k].w * f + p * vf[k].w;
    }
    m = mn;
}

template <int CPB>
__global__ __launch_bounds__(256)
void luong_pass1(const float* __restrict__ q,
                 const float* __restrict__ v,
                 const float* __restrict__ scale,
                 float* __restrict__ ws_acc,   // [BATCH*CPB][HD]
                 float* __restrict__ ws_m,     // [BATCH*CPB]
                 float* __restrict__ ws_l)     // [BATCH*CPB]
{
    constexpr int ROWS = SEQ / CPB;   // rows per block
    constexpr int RPW  = ROWS / 4;    // rows per wave (32 for CPB=32)
    static_assert(RPW >= 8 && (RPW % 4) == 0, "pipeline shape");

    const int blk  = blockIdx.x;
    const int b    = blk / CPB;
    const int ch   = blk % CPB;
    const int tid  = threadIdx.x;
    const int wid  = tid >> 6;
    const int lane = tid & 63;

    const float4* q4 = (const float4*)(q + (size_t)b * HD);
    float4 qf[4];
#pragma unroll
    for (int k = 0; k < 4; ++k) qf[k] = q4[k * 64 + lane];

    const int s0 = ch * ROWS + wid * RPW;
    const float* vb = v + (size_t)b * SEQ * HD;

    // hoist this wave's scale values when they fit one lane-register each
    float scl = 0.f;
    if constexpr (RPW <= 64) {
        scl = (lane < RPW) ? scale[s0 + lane] : 0.f;
    }
    auto get_scale = [&](int r) -> float {
        if constexpr (RPW <= 64) return __shfl(scl, r, 64);
        else                     return scale[s0 + r];
    };

    float  m = -INFINITY, l = 0.f;
    float4 acc[4];
#pragma unroll
    for (int k = 0; k < 4; ++k) acc[k] = make_float4(0.f, 0.f, 0.f, 0.f);

    // pair-wise ping-pong pipeline: 8 dwordx4 in flight while processing
    float4 A0[4], A1[4], B0[4], B1[4];
    load_row(vb, s0 + 0, lane, A0);
    load_row(vb, s0 + 1, lane, A1);
#pragma unroll 1
    for (int r = 0; r < RPW - 6; r += 4) {
        load_row(vb, s0 + r + 2, lane, B0);
        load_row(vb, s0 + r + 3, lane, B1);
        process_row(A0, qf, get_scale(r),     m, l, acc);
        process_row(A1, qf, get_scale(r + 1), m, l, acc);
        load_row(vb, s0 + r + 4, lane, A0);
        load_row(vb, s0 + r + 5, lane, A1);
        process_row(B0, qf, get_scale(r + 2), m, l, acc);
        process_row(B1, qf, get_scale(r + 3), m, l, acc);
    }
    // tail: A holds rows (RPW-4, RPW-3)
    load_row(vb, s0 + RPW - 2, lane, B0);
    load_row(vb, s0 + RPW - 1, lane, B1);
    process_row(A0, qf, get_scale(RPW - 4), m, l, acc);
    process_row(A1, qf, get_scale(RPW - 3), m, l, acc);
    process_row(B0, qf, get_scale(RPW - 2), m, l, acc);
    process_row(B1, qf, get_scale(RPW - 1), m, l, acc);

    // ---- combine the 4 waves of this block through LDS ----
    __shared__ float lds_m[4], lds_l[4];
    __shared__ float lds_acc[4][HD];
    if (lane == 0) { lds_m[wid] = m; lds_l[wid] = l; }
    __syncthreads();
    const float M  = fmaxf(fmaxf(lds_m[0], lds_m[1]), fmaxf(lds_m[2], lds_m[3]));
    const float fw = __expf(m - M);
    float4* la = (float4*)lds_acc[wid];
#pragma unroll
    for (int k = 0; k < 4; ++k) {
        float4 t;
        t.x = acc[k].x * fw; t.y = acc[k].y * fw;
        t.z = acc[k].z * fw; t.w = acc[k].w * fw;
        la[k * 64 + lane] = t;
    }
    __syncthreads();

    float lblk = 0.f;
#pragma unroll
    for (int w = 0; w < 4; ++w) lblk += lds_l[w] * __expf(lds_m[w] - M);

    const float4 a0 = ((const float4*)lds_acc[0])[tid];
    const float4 a1 = ((const float4*)lds_acc[1])[tid];
    const float4 a2 = ((const float4*)lds_acc[2])[tid];
    const float4 a3 = ((const float4*)lds_acc[3])[tid];
    float4 sum;
    sum.x = a0.x + a1.x + a2.x + a3.x;
    sum.y = a0.y + a1.y + a2.y + a3.y;
    sum.z = a0.z + a1.z + a2.z + a3.z;
    sum.w = a0.w + a1.w + a2.w + a3.w;
    ((float4*)(ws_acc + (size_t)blk * HD))[tid] = sum;
    if (tid == 0) { ws_m[blk] = M; ws_l[blk] = lblk; }
}

// ---------------------------------------------------------------------------
// Pass 2: combine the CPB partials of each batch and normalize. Tiny.
// ---------------------------------------------------------------------------
template <int CPB>
__global__ __launch_bounds__(256)
void luong_pass2(const float* __restrict__ ws_acc,
                 const float* __restrict__ ws_m,
                 const float* __restrict__ ws_l,
                 float* __restrict__ out)
{
    const int b   = blockIdx.x;
    const int tid = threadIdx.x;

    float M = -INFINITY;
#pragma unroll
    for (int i = 0; i < CPB; ++i) M = fmaxf(M, ws_m[b * CPB + i]);
    float T = 0.f;
#pragma unroll
    for (int i = 0; i < CPB; ++i) T += ws_l[b * CPB + i] * __expf(ws_m[b * CPB + i] - M);
    const float invT = 1.f / T;

    float4 sum = make_float4(0.f, 0.f, 0.f, 0.f);
#pragma unroll
    for (int i = 0; i < CPB; ++i) {
        const float wi = __expf(ws_m[b * CPB + i] - M) * invT;
        const float4 a = ((const float4*)(ws_acc + (size_t)(b * CPB + i) * HD))[tid];
        sum.x += wi * a.x; sum.y += wi * a.y;
        sum.z += wi * a.z; sum.w += wi * a.w;
    }
    ((float4*)(out + (size_t)b * HD))[tid] = sum;
}

// ---------------------------------------------------------------------------
template <int CPB>
static void launch_impl(const float* q, const float* v, const float* scale,
                        float* out, float* ws, hipStream_t stream)
{
    const int NB = BATCH * CPB;
    float* ws_acc = ws;
    float* ws_m   = ws + (size_t)NB * HD;
    float* ws_l   = ws_m + NB;
    luong_pass1<CPB><<<NB, 256, 0, stream>>>(q, v, scale, ws_acc, ws_m, ws_l);
    luong_pass2<CPB><<<BATCH, 256, 0, stream>>>(ws_acc, ws_m, ws_l, out);
}

extern "C" void kernel_launch(void* const* d_in, const int* in_sizes, int n_in,
                              void* d_out, int out_size, void* d_ws, size_t ws_size,
                              hipStream_t stream)
{
    const float* q     = (const float*)d_in[0];   // [B, H]
    const float* v     = (const float*)d_in[1];   // [B, S, H]
    const float* scale = (const float*)d_in[2];   // [S, 1]
    float* out = (float*)d_out;                   // [B, H]
    float* ws  = (float*)d_ws;

    int cpb = 32;
    while (cpb > 1 &&
           (size_t)BATCH * cpb * (HD + 2) * sizeof(float) > ws_size)
        cpb >>= 1;

    switch (cpb) {
        case 32: launch_impl<32>(q, v, scale, out, ws, stream); break;
        case 16: launch_impl<16>(q, v, scale, out, ws, stream); break;
        case 8:  launch_impl<8>(q, v, scale, out, ws, stream); break;
        case 4:  launch_impl<4>(q, v, scale, out, ws, stream); break;
        case 2:  launch_impl<2>(q, v, scale, out, ws, stream); break;
        default: launch_impl<1>(q, v, scale, out, ws, stream); break;
    }
}